// Round 1
// baseline (993.341 us; speedup 1.0000x reference)
//
#include <hip/hip_runtime.h>
#include <hip/hip_bf16.h>

// BilinearChebConv: out[o,m,n] = sum_ij theta[i,j,0,o] * (T_i(Lr) @ X @ T_j(Lc))[m,n] + bias[o]
// M=N=1536, P=4, OUT=32. Strategy:
//  - Chebyshev recursion applied directly to planes (no basis matrices).
//  - Stage 1 transposed (Yt_k = 2*Yt_{k-1}@Lr - Yt_{k-2}) so B operand is always the
//    symmetric Laplacian -> gemm_bt (B^T == B) with contiguous LDS fragment reads.
//  - Stage 2 batched: 5 chains stacked -> M=7680 GEMMs.
//  - bf16 MFMA GEMMs (16x16x32), fp32 carry for the 2x-prev recursion.
//  - Final 25->32 theta contraction, memory-bound.
// Workspace: 29 bf16 planes + 15 fp32 planes = 266 MiB.

#define NDIM 1536
#define PM (NDIM * NDIM)  // 2359296

typedef __attribute__((ext_vector_type(8))) short bf16x8;
typedef __attribute__((ext_vector_type(4))) float f32x4;

__device__ inline void gload_lds16(const void* g, void* l) {
  __builtin_amdgcn_global_load_lds(
      (const __attribute__((address_space(1))) void*)g,
      (__attribute__((address_space(3))) void*)l, 16, 0, 0);
}

__device__ inline unsigned short f2bf(float f) {
  __hip_bfloat16 h = __float2bfloat16(f);
  return *reinterpret_cast<unsigned short*>(&h);
}

// C = A @ B  (optionally C = 2*A@B - Cprev), A: Mx1536 bf16 row-major,
// B: 1536x1536 bf16 SYMMETRIC (read as B^T rows). Writes fp32 (optional) + bf16.
__global__ __launch_bounds__(256) void gemm_bt(
    const unsigned short* __restrict__ A, const unsigned short* __restrict__ B,
    const float* __restrict__ Cprev,   // null -> plain A@B
    float* __restrict__ out32,         // null -> skip fp32 store
    unsigned short* __restrict__ out16) {
  __shared__ __align__(16) unsigned short As[128 * 32];
  __shared__ __align__(16) unsigned short Bs[128 * 32];
  const int tid = threadIdx.x;
  const int lane = tid & 63;
  const int wave = tid >> 6;
  const int wm = wave >> 1, wn = wave & 1;
  const int gm0 = blockIdx.y * 128;
  const int gn0 = blockIdx.x * 128;
  const int q = lane >> 4;       // 0..3
  const int rowl = lane & 15;    // 0..15

  f32x4 acc[4][4] = {};

  for (int k0 = 0; k0 < NDIM; k0 += 32) {
#pragma unroll
    for (int l = 0; l < 2; ++l) {
      int f = l * 256 + wave * 64 + lane;     // flat 16B chunk id, 512 per tile
      int r = f >> 2, kc = f & 3;             // row, 16B chunk within 64B row
      const unsigned short* ga = A + (size_t)(gm0 + r) * NDIM + k0 + kc * 8;
      const unsigned short* gb = B + (size_t)(gn0 + r) * NDIM + k0 + kc * 8;
      // LDS dest: wave-uniform base + lane*16 (contiguous chunk order)
      unsigned short* la = &As[(size_t)(l * 256 + wave * 64) * 8];
      unsigned short* lb = &Bs[(size_t)(l * 256 + wave * 64) * 8];
      gload_lds16(ga, la);
      gload_lds16(gb, lb);
    }
    __syncthreads();
    bf16x8 af[4], bfv[4];
#pragma unroll
    for (int t = 0; t < 4; ++t) {
      af[t] = *(const bf16x8*)&As[(wm * 64 + t * 16 + rowl) * 32 + q * 8];
      bfv[t] = *(const bf16x8*)&Bs[(wn * 64 + t * 16 + rowl) * 32 + q * 8];
    }
#pragma unroll
    for (int mt = 0; mt < 4; ++mt)
#pragma unroll
      for (int nt = 0; nt < 4; ++nt)
        acc[mt][nt] = __builtin_amdgcn_mfma_f32_16x16x32_bf16(
            af[mt], bfv[nt], acc[mt][nt], 0, 0, 0);
    __syncthreads();
  }

  // C/D layout: col = lane&15, row = (lane>>4)*4 + reg
#pragma unroll
  for (int mt = 0; mt < 4; ++mt) {
#pragma unroll
    for (int nt = 0; nt < 4; ++nt) {
#pragma unroll
      for (int v = 0; v < 4; ++v) {
        int row = gm0 + wm * 64 + mt * 16 + q * 4 + v;
        int col = gn0 + wn * 64 + nt * 16 + rowl;
        size_t idx = (size_t)row * NDIM + col;
        float val = acc[mt][nt][v];
        if (Cprev) val = 2.0f * val - Cprev[idx];
        if (out32) out32[idx] = val;
        out16[idx] = f2bf(val);
      }
    }
  }
}

// out[b][a] = in[a][b], fp32 in -> fp32 out + bf16 out (both transposed)
__global__ void transpose_cast(const float* __restrict__ in,
                               float* __restrict__ out32,
                               unsigned short* __restrict__ out16) {
  __shared__ float tile[32][33];
  int bx = blockIdx.x, by = blockIdx.y;
  int tx = threadIdx.x;
#pragma unroll
  for (int r = threadIdx.y; r < 32; r += 8)
    tile[r][tx] = in[(size_t)(by * 32 + r) * NDIM + bx * 32 + tx];
  __syncthreads();
  int ox = by * 32 + tx;
#pragma unroll
  for (int r = threadIdx.y; r < 32; r += 8) {
    float v = tile[tx][r];
    size_t idx = (size_t)(bx * 32 + r) * NDIM + ox;
    out32[idx] = v;
    out16[idx] = f2bf(v);
  }
}

__global__ void cast_bf16_k(const float* __restrict__ in,
                            unsigned short* __restrict__ out) {
  int i = (blockIdx.x * 256 + threadIdx.x) * 4;
  float4 v = *(const float4*)(in + i);
  ushort4 r;
  r.x = f2bf(v.x); r.y = f2bf(v.y); r.z = f2bf(v.z); r.w = f2bf(v.w);
  *(ushort4*)(out + i) = r;
}

__global__ void cast_copy_k(const float* __restrict__ in,
                            unsigned short* __restrict__ ob,
                            float* __restrict__ of) {
  int i = (blockIdx.x * 256 + threadIdx.x) * 4;
  float4 v = *(const float4*)(in + i);
  ushort4 r;
  r.x = f2bf(v.x); r.y = f2bf(v.y); r.z = f2bf(v.z); r.w = f2bf(v.w);
  *(ushort4*)(ob + i) = r;
  *(float4*)(of + i) = v;
}

// Z: 25 bf16 planes, plane c = j*5+i. theta[(i*5+j)*32+o].
__global__ void combine_k(const unsigned short* __restrict__ Z,
                          const float* __restrict__ theta,
                          const float* __restrict__ bias,
                          float* __restrict__ out) {
  const size_t p0 = (size_t)(blockIdx.x * 256 + threadIdx.x) * 2;
  float z0[25], z1[25];
#pragma unroll
  for (int c = 0; c < 25; ++c) {
    unsigned int u = *(const unsigned int*)(Z + (size_t)c * PM + p0);
    z0[c] = __uint_as_float(u << 16);
    z1[c] = __uint_as_float(u & 0xffff0000u);
  }
  for (int o = 0; o < 32; ++o) {
    float a0 = bias[o], a1 = a0;
#pragma unroll
    for (int j = 0; j < 5; ++j)
#pragma unroll
      for (int i = 0; i < 5; ++i) {
        float t = theta[(i * 5 + j) * 32 + o];  // uniform -> s_load
        int c = j * 5 + i;
        a0 += t * z0[c];
        a1 += t * z1[c];
      }
    float2 w;
    w.x = a0; w.y = a1;
    *(float2*)(out + (size_t)o * PM + p0) = w;
  }
}

extern "C" void kernel_launch(void* const* d_in, const int* in_sizes, int n_in,
                              void* d_out, int out_size, void* d_ws, size_t ws_size,
                              hipStream_t stream) {
  (void)in_sizes; (void)n_in; (void)out_size; (void)ws_size;
  const float* X = (const float*)d_in[0];
  const float* Lr = (const float*)d_in[1];
  const float* Lc = (const float*)d_in[2];
  const float* theta = (const float*)d_in[3];
  const float* bias = (const float*)d_in[4];
  float* out = (float*)d_out;

  // Workspace layout (needs 118*PM bytes = 266 MiB)
  unsigned short* Zall = (unsigned short*)d_ws;       // 25 planes bf16: c=j*5+i
  unsigned short* Lr16 = Zall + (size_t)25 * PM;
  unsigned short* Lc16 = Lr16 + (size_t)PM;
  unsigned short* ytb0 = Lc16 + (size_t)PM;           // rotating stage-1 bf16 A bufs
  unsigned short* ytb1 = ytb0 + (size_t)PM;
  float* pool = (float*)(ytb1 + (size_t)PM);          // 15 fp32 planes
  // pool[0..4]=S0 (X,Y1..Y4), pool[5..9]=Yt chain fp32 then S1, pool[10..14]=S2

  dim3 tgrid(48, 48), tblk(32, 8);
  dim3 g1(12, 12), g2(12, 60);

  cast_bf16_k<<<PM / 1024, 256, 0, stream>>>(Lr, Lr16);
  cast_bf16_k<<<PM / 1024, 256, 0, stream>>>(Lc, Lc16);
  // S0 slot0 = X fp32 copy; Zall[c=0] = bf16(X)
  cast_copy_k<<<PM / 1024, 256, 0, stream>>>(X, Zall, pool);
  // Xt (Yt_0): fp32 -> pool[5], bf16 -> ytb0
  transpose_cast<<<tgrid, tblk, 0, stream>>>(X, pool + (size_t)5 * PM, ytb0);

  // Stage 1: Yt_k = 2*Yt_{k-1}@Lr - Yt_{k-2}  (Yt_1 plain)
  gemm_bt<<<g1, 256, 0, stream>>>(ytb0, Lr16, nullptr, pool + (size_t)6 * PM, ytb1);
  gemm_bt<<<g1, 256, 0, stream>>>(ytb1, Lr16, pool + (size_t)5 * PM, pool + (size_t)7 * PM, ytb0);
  gemm_bt<<<g1, 256, 0, stream>>>(ytb0, Lr16, pool + (size_t)6 * PM, pool + (size_t)8 * PM, ytb1);
  gemm_bt<<<g1, 256, 0, stream>>>(ytb1, Lr16, pool + (size_t)7 * PM, pool + (size_t)9 * PM, ytb0);

  // Transpose back: Y_i = Yt_i^T -> S0 slot i (fp32) + Zall[c=i] (bf16)
  for (int i = 1; i <= 4; ++i)
    transpose_cast<<<tgrid, tblk, 0, stream>>>(
        pool + (size_t)(5 + i) * PM, pool + (size_t)i * PM, Zall + (size_t)i * PM);

  // Stage 2 (batched over i, M=7680): Z_j = 2*Z_{j-1}@Lc - Z_{j-2}  (Z_1 plain)
  gemm_bt<<<g2, 256, 0, stream>>>(Zall, Lc16, nullptr,
                                  pool + (size_t)5 * PM, Zall + (size_t)5 * PM);
  gemm_bt<<<g2, 256, 0, stream>>>(Zall + (size_t)5 * PM, Lc16, pool,
                                  pool + (size_t)10 * PM, Zall + (size_t)10 * PM);
  gemm_bt<<<g2, 256, 0, stream>>>(Zall + (size_t)10 * PM, Lc16, pool + (size_t)5 * PM,
                                  nullptr, Zall + (size_t)15 * PM);
  gemm_bt<<<g2, 256, 0, stream>>>(Zall + (size_t)15 * PM, Lc16, pool + (size_t)10 * PM,
                                  nullptr, Zall + (size_t)20 * PM);

  // Final contraction 25 -> 32 channels
  combine_k<<<PM / 512, 256, 0, stream>>>(Zall, theta, bias, out);
}